// Round 2
// baseline (194.350 us; speedup 1.0000x reference)
//
#include <hip/hip_runtime.h>
#include <hip/hip_bf16.h>
#include <math.h>

// Fused attention-gate, wave-independent version:
//   g = BN(in_g @ Wg + bg); x = BN(in_x @ Wx + bx); s = relu(g+x)
//   psi = sigmoid(BN(s @ Wp + bp)); out = x * psi
// Each wave owns 16 pixels x full F=128, K=256. No LDS, no barriers.
// A fragments loaded per-lane from global (fp32 -> bf16 inline); B from
// L2-resident folded bf16 weights (transposed f-major).

typedef __bf16 bf16x8 __attribute__((ext_vector_type(8)));
typedef float f32x4 __attribute__((ext_vector_type(4)));

__device__ __forceinline__ unsigned short f2bf(float f) {
  union { float f; unsigned u; } v; v.f = f;
  unsigned r = (v.u + 0x7fffu + ((v.u >> 16) & 1u)) >> 16;
  return (unsigned short)r;
}

// ---------------- pre-kernel: fold BN into weights ----------------
__global__ __launch_bounds__(256) void fold_weights(
    const float* __restrict__ Wg, const float* __restrict__ bg,
    const float* __restrict__ gg, const float* __restrict__ beg,
    const float* __restrict__ mg, const float* __restrict__ vg,
    const float* __restrict__ Wx, const float* __restrict__ bx,
    const float* __restrict__ gx, const float* __restrict__ bex,
    const float* __restrict__ mx, const float* __restrict__ vx,
    const float* __restrict__ Wp, const float* __restrict__ bp,
    const float* __restrict__ gp, const float* __restrict__ bep,
    const float* __restrict__ mp, const float* __restrict__ vp,
    unsigned short* __restrict__ Wtg, unsigned short* __restrict__ Wtx,
    float* __restrict__ cg, float* __restrict__ cx,
    float* __restrict__ wps, float* __restrict__ cps) {
  int idx = blockIdx.x * 256 + threadIdx.x;  // 0..32767 = 256*128
  int c = idx >> 7;    // Cin index
  int f = idx & 127;   // F index
  float ivg = gg[f] * rsqrtf(vg[f] + 1e-3f);
  float ivx = gx[f] * rsqrtf(vx[f] + 1e-3f);
  // store transposed (f-major) so B-fragments are 8 contiguous k per lane
  Wtg[f * 256 + c] = f2bf(Wg[c * 128 + f] * ivg);
  Wtx[f * 256 + c] = f2bf(Wx[c * 128 + f] * ivx);
  if (idx < 128) {
    float ivg2 = gg[idx] * rsqrtf(vg[idx] + 1e-3f);
    float ivx2 = gx[idx] * rsqrtf(vx[idx] + 1e-3f);
    cg[idx] = bg[idx] * ivg2 + beg[idx] - mg[idx] * ivg2;
    cx[idx] = bx[idx] * ivx2 + bex[idx] - mx[idx] * ivx2;
    float ip = gp[0] * rsqrtf(vp[0] + 1e-3f);
    wps[idx] = Wp[idx] * ip;
    if (idx == 0) cps[0] = bp[0] * ip + bep[0] - mp[0] * ip;
  }
}

// ---------------- main fused kernel ----------------
// 256 threads = 4 independent waves; each wave: 16 pixels x 128 F.
__global__ __launch_bounds__(256, 3) void attn_gate_main(
    const float* __restrict__ ing, const float* __restrict__ inx,
    const unsigned short* __restrict__ Wtg, const unsigned short* __restrict__ Wtx,
    const float* __restrict__ cgp, const float* __restrict__ cxp,
    const float* __restrict__ wpp, const float* __restrict__ cpp,
    float* __restrict__ out) {
  const int tid = threadIdx.x;
  const int lane = tid & 63;
  const int wid = tid >> 6;
  const int l15 = lane & 15, l4 = lane >> 4;
  const long p0 = ((long)blockIdx.x * 4 + wid) * 16;  // first pixel of wave

  // per-lane A base: row = p0 + l15, k base = l4*8
  const float* pg = ing + (p0 + l15) * 256 + l4 * 8;
  const float* px = inx + (p0 + l15) * 256 + l4 * 8;
  // per-lane B base: f = l15 (+nf*16), k base = l4*8
  const unsigned short* bg_base = Wtg + l15 * 256 + l4 * 8;
  const unsigned short* bx_base = Wtx + l15 * 256 + l4 * 8;

  f32x4 accg[8] = {{0.f,0.f,0.f,0.f}};
  f32x4 accx[8] = {{0.f,0.f,0.f,0.f}};
  #pragma unroll
  for (int nf = 0; nf < 8; ++nf) { accg[nf] = f32x4{0.f,0.f,0.f,0.f}; accx[nf] = f32x4{0.f,0.f,0.f,0.f}; }

  #pragma unroll
  for (int ks = 0; ks < 8; ++ks) {
    const int kb = ks * 32;  // k offset of this step (per-lane adds l4*8)
    float4 g0 = *reinterpret_cast<const float4*>(pg + kb);
    float4 g1 = *reinterpret_cast<const float4*>(pg + kb + 4);
    float4 x0 = *reinterpret_cast<const float4*>(px + kb);
    float4 x1 = *reinterpret_cast<const float4*>(px + kb + 4);
    bf16x8 ag, ax;
    ag[0]=(__bf16)g0.x; ag[1]=(__bf16)g0.y; ag[2]=(__bf16)g0.z; ag[3]=(__bf16)g0.w;
    ag[4]=(__bf16)g1.x; ag[5]=(__bf16)g1.y; ag[6]=(__bf16)g1.z; ag[7]=(__bf16)g1.w;
    ax[0]=(__bf16)x0.x; ax[1]=(__bf16)x0.y; ax[2]=(__bf16)x0.z; ax[3]=(__bf16)x0.w;
    ax[4]=(__bf16)x1.x; ax[5]=(__bf16)x1.y; ax[6]=(__bf16)x1.z; ax[7]=(__bf16)x1.w;

    #pragma unroll
    for (int nf = 0; nf < 8; ++nf) {
      bf16x8 bgf = *reinterpret_cast<const bf16x8*>(bg_base + nf * 4096 + kb);
      bf16x8 bxf = *reinterpret_cast<const bf16x8*>(bx_base + nf * 4096 + kb);
      accg[nf] = __builtin_amdgcn_mfma_f32_16x16x32_bf16(ag, bgf, accg[nf], 0, 0, 0);
      accx[nf] = __builtin_amdgcn_mfma_f32_16x16x32_bf16(ax, bxf, accx[nf], 0, 0, 0);
    }
  }

  // ---- epilogue: bias, relu(g+x), psi dot (wave-local), sigmoid, store ----
  float wpv[8], cgv[8], cxv[8];
  #pragma unroll
  for (int nf = 0; nf < 8; ++nf) {
    int f = nf * 16 + l15;
    wpv[nf] = wpp[f]; cgv[nf] = cgp[f]; cxv[nf] = cxp[f];
  }
  const float cpsv = cpp[0];

  #pragma unroll
  for (int reg = 0; reg < 4; ++reg) {
    float part = 0.f;
    #pragma unroll
    for (int nf = 0; nf < 8; ++nf) {
      float gv = accg[nf][reg] + cgv[nf];
      float xv = accx[nf][reg] + cxv[nf];
      float s = gv + xv;
      s = s > 0.f ? s : 0.f;
      part += s * wpv[nf];
    }
    // sum across the 16-lane group (XOR of bits 0..3 stays in-group)
    part += __shfl_xor(part, 1);
    part += __shfl_xor(part, 2);
    part += __shfl_xor(part, 4);
    part += __shfl_xor(part, 8);
    float psi = 1.f / (1.f + __expf(-(part + cpsv)));
    const int row = l4 * 4 + reg;           // C/D layout: row=(lane>>4)*4+reg
    float* orow = out + (p0 + row) * 128;
    #pragma unroll
    for (int nf = 0; nf < 8; ++nf) {
      orow[nf * 16 + l15] = (accx[nf][reg] + cxv[nf]) * psi;
    }
  }
}

extern "C" void kernel_launch(void* const* d_in, const int* in_sizes, int n_in,
                              void* d_out, int out_size, void* d_ws, size_t ws_size,
                              hipStream_t stream) {
  const float* ing = (const float*)d_in[0];
  const float* inx = (const float*)d_in[1];
  char* ws = (char*)d_ws;
  unsigned short* Wtg = (unsigned short*)ws;                 // 64 KB
  unsigned short* Wtx = (unsigned short*)(ws + 65536);       // 64 KB
  float* cg  = (float*)(ws + 131072);                        // 512 B
  float* cx  = (float*)(ws + 131584);                        // 512 B
  float* wps = (float*)(ws + 132096);                        // 512 B
  float* cps = (float*)(ws + 132608);                        // 4 B

  fold_weights<<<128, 256, 0, stream>>>(
      (const float*)d_in[2],  (const float*)d_in[3],  (const float*)d_in[4],
      (const float*)d_in[5],  (const float*)d_in[6],  (const float*)d_in[7],
      (const float*)d_in[8],  (const float*)d_in[9],  (const float*)d_in[10],
      (const float*)d_in[11], (const float*)d_in[12], (const float*)d_in[13],
      (const float*)d_in[14], (const float*)d_in[15], (const float*)d_in[16],
      (const float*)d_in[17], (const float*)d_in[18], (const float*)d_in[19],
      Wtg, Wtx, cg, cx, wps, cps);

  const int npix = in_sizes[0] / 256;   // 131072
  attn_gate_main<<<npix / 64, 256, 0, stream>>>(
      ing, inx, Wtg, Wtx, cg, cx, wps, cps, (float*)d_out);
}

// Round 3
// 94.376 us; speedup vs baseline: 2.0593x; 2.0593x over previous
//
#include <hip/hip_runtime.h>
#include <hip/hip_bf16.h>
#include <math.h>

// Fused attention-gate:
//   g = BN(in_g @ Wg); x = BN(in_x @ Wx); s = relu(g+x)
//   psi = sigmoid(BN(s @ Wp)); out = x * psi
// Round 3: all global accesses wave-contiguous.
//  - B pre-formatted into MFMA fragment-linear order (1KB coalesced wave loads, L2-hot)
//  - A staged to LDS in K-chunks of 64, double-buffered, XOR-swizzled
//  - block = 256 thr = 4 waves (2M x 2N), tile 32 px x 128 F, LDS 16.5KB

typedef __bf16 bf16x8 __attribute__((ext_vector_type(8)));
typedef float f32x4 __attribute__((ext_vector_type(4)));

__device__ __forceinline__ unsigned short f2bf(float f) {
  union { float f; unsigned u; } v; v.f = f;
  unsigned r = (v.u + 0x7fffu + ((v.u >> 16) & 1u)) >> 16;
  return (unsigned short)r;
}

// ---------------- pre-kernel: fold BN into weights, fragment-linear ----------------
// Bfrag layout: [ftile(8)][ksg(8)][lane(64)][slot(8)] bf16  (per table, 64KB)
// lane l of fragment (ftile,ksg) holds Wt[f=ftile*16+(l&15)][k=ksg*32+(l>>4)*8+slot]
__global__ __launch_bounds__(256) void fold_weights(
    const float* __restrict__ Wg, const float* __restrict__ bg,
    const float* __restrict__ gg, const float* __restrict__ beg,
    const float* __restrict__ mg, const float* __restrict__ vg,
    const float* __restrict__ Wx, const float* __restrict__ bx,
    const float* __restrict__ gx, const float* __restrict__ bex,
    const float* __restrict__ mx, const float* __restrict__ vx,
    const float* __restrict__ Wp, const float* __restrict__ bp,
    const float* __restrict__ gp, const float* __restrict__ bep,
    const float* __restrict__ mp, const float* __restrict__ vp,
    unsigned short* __restrict__ Bfg, unsigned short* __restrict__ Bfx,
    float* __restrict__ cg, float* __restrict__ cx,
    float* __restrict__ wps, float* __restrict__ cps) {
  int idx = blockIdx.x * 256 + threadIdx.x;  // 0..32767 = 256(c) * 128(f)
  int c = idx >> 7;    // Cin / k index
  int f = idx & 127;   // F index
  float ivg = gg[f] * rsqrtf(vg[f] + 1e-3f);
  float ivx = gx[f] * rsqrtf(vx[f] + 1e-3f);
  int ftile = f >> 4;
  int ksg = c >> 5;
  int lane = (((c >> 3) & 3) << 4) | (f & 15);
  int slot = c & 7;
  int off = ((ftile * 8 + ksg) * 64 + lane) * 8 + slot;
  Bfg[off] = f2bf(Wg[c * 128 + f] * ivg);
  Bfx[off] = f2bf(Wx[c * 128 + f] * ivx);
  if (idx < 128) {
    float ivg2 = gg[idx] * rsqrtf(vg[idx] + 1e-3f);
    float ivx2 = gx[idx] * rsqrtf(vx[idx] + 1e-3f);
    cg[idx] = bg[idx] * ivg2 + beg[idx] - mg[idx] * ivg2;
    cx[idx] = bx[idx] * ivx2 + bex[idx] - mx[idx] * ivx2;
    float ip = gp[0] * rsqrtf(vp[0] + 1e-3f);
    wps[idx] = Wp[idx] * ip;
    if (idx == 0) cps[0] = bp[0] * ip + bep[0] - mp[0] * ip;
  }
}

// ---------------- main fused kernel ----------------
__global__ __launch_bounds__(256, 4) void attn_gate_main(
    const float* __restrict__ ing, const float* __restrict__ inx,
    const unsigned short* __restrict__ Bfg, const unsigned short* __restrict__ Bfx,
    const float* __restrict__ cgp, const float* __restrict__ cxp,
    const float* __restrict__ wpp, const float* __restrict__ cpp,
    float* __restrict__ out) {
  // A chunks: [buf][tbl][32 rows][64 k] bf16 = 4KB each, 16KB total
  __shared__ __align__(16) short lA[2][2][2048];
  __shared__ float psum[32][2];
  __shared__ float psiS[32];

  const int tid = threadIdx.x;
  const int lane = tid & 63;
  const int wid = tid >> 6;
  const int wm = wid >> 1, wn = wid & 1;   // 2(M) x 2(N) waves
  const int l15 = lane & 15, l4 = lane >> 4;
  const long p0 = (long)blockIdx.x * 32;   // first pixel of tile

  // staging geometry: thread t covers row=t>>3 (0..31), k0=(t&7)*8 of [32][64]
  const int srow = tid >> 3;
  const int sk0 = (tid & 7) * 8;
  const int soff = ((srow << 7) | (sk0 << 1)) ^ ((srow & 7) << 4);
  const float* sg_base = ing + (p0 + srow) * 256 + sk0;
  const float* sx_base = inx + (p0 + srow) * 256 + sk0;

  auto stage = [&](int kc, int buf) {
    const float* sg = sg_base + kc * 64;
    const float* sx = sx_base + kc * 64;
    float4 g0 = *reinterpret_cast<const float4*>(sg);
    float4 g1 = *reinterpret_cast<const float4*>(sg + 4);
    float4 x0 = *reinterpret_cast<const float4*>(sx);
    float4 x1 = *reinterpret_cast<const float4*>(sx + 4);
    bf16x8 pg, px;
    pg[0]=(__bf16)g0.x; pg[1]=(__bf16)g0.y; pg[2]=(__bf16)g0.z; pg[3]=(__bf16)g0.w;
    pg[4]=(__bf16)g1.x; pg[5]=(__bf16)g1.y; pg[6]=(__bf16)g1.z; pg[7]=(__bf16)g1.w;
    px[0]=(__bf16)x0.x; px[1]=(__bf16)x0.y; px[2]=(__bf16)x0.z; px[3]=(__bf16)x0.w;
    px[4]=(__bf16)x1.x; px[5]=(__bf16)x1.y; px[6]=(__bf16)x1.z; px[7]=(__bf16)x1.w;
    *reinterpret_cast<bf16x8*>((char*)&lA[buf][0][0] + soff) = pg;
    *reinterpret_cast<bf16x8*>((char*)&lA[buf][1][0] + soff) = px;
  };

  f32x4 accg[4], accx[4];
  #pragma unroll
  for (int nf = 0; nf < 4; ++nf) { accg[nf] = f32x4{0.f,0.f,0.f,0.f}; accx[nf] = f32x4{0.f,0.f,0.f,0.f}; }

  const int rowA = wm * 16 + l15;
  const int rowSwz = (rowA & 7) << 4;

  stage(0, 0);
  __syncthreads();

  #pragma unroll
  for (int kc = 0; kc < 4; ++kc) {
    const int buf = kc & 1;
    if (kc < 3) stage(kc + 1, buf ^ 1);
    #pragma unroll
    for (int ks2 = 0; ks2 < 2; ++ks2) {
      const int colb = ks2 * 64 + l4 * 16;                 // byte col in 128B row
      const int offA = ((rowA << 7) | colb) ^ rowSwz;
      bf16x8 ag = *reinterpret_cast<const bf16x8*>((char*)&lA[buf][0][0] + offA);
      bf16x8 ax = *reinterpret_cast<const bf16x8*>((char*)&lA[buf][1][0] + offA);
      const int ksg = kc * 2 + ks2;
      #pragma unroll
      for (int nf = 0; nf < 4; ++nf) {
        const int ftile = wn * 4 + nf;
        const int foff = ((ftile * 8 + ksg) * 64 + lane) * 8;
        bf16x8 bgf = *reinterpret_cast<const bf16x8*>(Bfg + foff);
        bf16x8 bxf = *reinterpret_cast<const bf16x8*>(Bfx + foff);
        accg[nf] = __builtin_amdgcn_mfma_f32_16x16x32_bf16(ag, bgf, accg[nf], 0, 0, 0);
        accx[nf] = __builtin_amdgcn_mfma_f32_16x16x32_bf16(ax, bxf, accx[nf], 0, 0, 0);
      }
    }
    __syncthreads();
  }

  // ---- epilogue: bias, relu(g+x), psi dot, cross-wn combine, sigmoid, store ----
  float wpv[4], cgv[4], cxv[4];
  #pragma unroll
  for (int nf = 0; nf < 4; ++nf) {
    int f = wn * 64 + nf * 16 + l15;
    wpv[nf] = wpp[f]; cgv[nf] = cgp[f]; cxv[nf] = cxp[f];
  }

  #pragma unroll
  for (int reg = 0; reg < 4; ++reg) {
    float part = 0.f;
    #pragma unroll
    for (int nf = 0; nf < 4; ++nf) {
      float gv = accg[nf][reg] + cgv[nf];
      float xv = accx[nf][reg] + cxv[nf];
      float s = gv + xv;
      s = s > 0.f ? s : 0.f;
      part += s * wpv[nf];
    }
    part += __shfl_xor(part, 1);
    part += __shfl_xor(part, 2);
    part += __shfl_xor(part, 4);
    part += __shfl_xor(part, 8);
    if (l15 == 0) psum[wm * 16 + l4 * 4 + reg][wn] = part;
  }
  __syncthreads();
  if (tid < 32) {
    float z = psum[tid][0] + psum[tid][1] + cpp[0];
    psiS[tid] = 1.f / (1.f + __expf(-z));
  }
  __syncthreads();

  #pragma unroll
  for (int reg = 0; reg < 4; ++reg) {
    const int brow = wm * 16 + l4 * 4 + reg;
    const float ps = psiS[brow];
    float* orow = out + (p0 + brow) * 128 + wn * 64;
    #pragma unroll
    for (int nf = 0; nf < 4; ++nf) {
      orow[nf * 16 + l15] = (accx[nf][reg] + cxv[nf]) * ps;
    }
  }
}

extern "C" void kernel_launch(void* const* d_in, const int* in_sizes, int n_in,
                              void* d_out, int out_size, void* d_ws, size_t ws_size,
                              hipStream_t stream) {
  const float* ing = (const float*)d_in[0];
  const float* inx = (const float*)d_in[1];
  char* ws = (char*)d_ws;
  unsigned short* Bfg = (unsigned short*)ws;                 // 64 KB
  unsigned short* Bfx = (unsigned short*)(ws + 65536);       // 64 KB
  float* cg  = (float*)(ws + 131072);                        // 512 B
  float* cx  = (float*)(ws + 131584);                        // 512 B
  float* wps = (float*)(ws + 132096);                        // 512 B
  float* cps = (float*)(ws + 132608);                        // 4 B

  fold_weights<<<128, 256, 0, stream>>>(
      (const float*)d_in[2],  (const float*)d_in[3],  (const float*)d_in[4],
      (const float*)d_in[5],  (const float*)d_in[6],  (const float*)d_in[7],
      (const float*)d_in[8],  (const float*)d_in[9],  (const float*)d_in[10],
      (const float*)d_in[11], (const float*)d_in[12], (const float*)d_in[13],
      (const float*)d_in[14], (const float*)d_in[15], (const float*)d_in[16],
      (const float*)d_in[17], (const float*)d_in[18], (const float*)d_in[19],
      Bfg, Bfx, cg, cx, wps, cps);

  const int npix = in_sizes[0] / 256;   // 131072
  attn_gate_main<<<npix / 32, 256, 0, stream>>>(
      ing, inx, Bfg, Bfx, cg, cx, wps, cps, (float*)d_out);
}

// Round 4
// 74.213 us; speedup vs baseline: 2.6188x; 1.2717x over previous
//
#include <hip/hip_runtime.h>
#include <hip/hip_bf16.h>
#include <math.h>

// Fused attention-gate, round 4: weights-in-registers.
//   g = BN(in_g @ Wg); x = BN(in_x @ Wx); s = relu(g+x)
//   psi = sigmoid(BN(s @ Wp)); out = x * psi
// C'[f][px] = W^T . pix^T : W is the MFMA A-operand, held in VGPRs (64/lane
// per wave for both tensors, full K=256). Pixels staged to swizzled LDS as
// the B-operand, 16-px tiles, double-buffered, 4 tiles per block.
// Inner loop has ZERO global loads -> no L2 latency on the critical path.

typedef __bf16 bf16x8 __attribute__((ext_vector_type(8)));
typedef float f32x4 __attribute__((ext_vector_type(4)));

__device__ __forceinline__ unsigned short f2bf(float f) {
  union { float f; unsigned u; } v; v.f = f;
  unsigned r = (v.u + 0x7fffu + ((v.u >> 16) & 1u)) >> 16;
  return (unsigned short)r;
}

__device__ __forceinline__ bf16x8 cvt8(float4 a, float4 b) {
  bf16x8 r;
  r[0]=(__bf16)a.x; r[1]=(__bf16)a.y; r[2]=(__bf16)a.z; r[3]=(__bf16)a.w;
  r[4]=(__bf16)b.x; r[5]=(__bf16)b.y; r[6]=(__bf16)b.z; r[7]=(__bf16)b.w;
  return r;
}

// ---------------- pre-kernel: fold BN into weights, fragment-linear ----------------
// Wfrag layout: [ftile(8)][ksg(8)][lane(64)][slot(8)] bf16 (64KB per tensor)
// lane l of fragment (ftile,ksg) holds W'[f=ftile*16+(l&15)][k=ksg*32+(l>>4)*8+slot]
__global__ __launch_bounds__(256) void fold_weights(
    const float* __restrict__ Wg, const float* __restrict__ bg,
    const float* __restrict__ gg, const float* __restrict__ beg,
    const float* __restrict__ mg, const float* __restrict__ vg,
    const float* __restrict__ Wx, const float* __restrict__ bx,
    const float* __restrict__ gx, const float* __restrict__ bex,
    const float* __restrict__ mx, const float* __restrict__ vx,
    const float* __restrict__ Wp, const float* __restrict__ bp,
    const float* __restrict__ gp, const float* __restrict__ bep,
    const float* __restrict__ mp, const float* __restrict__ vp,
    unsigned short* __restrict__ Bfg, unsigned short* __restrict__ Bfx,
    float* __restrict__ cg, float* __restrict__ cx,
    float* __restrict__ wps, float* __restrict__ cps) {
  int idx = blockIdx.x * 256 + threadIdx.x;  // 0..32767 = 256(c) * 128(f)
  int c = idx >> 7;    // Cin / k index
  int f = idx & 127;   // F index
  float ivg = gg[f] * rsqrtf(vg[f] + 1e-3f);
  float ivx = gx[f] * rsqrtf(vx[f] + 1e-3f);
  int ftile = f >> 4;
  int ksg = c >> 5;
  int lane = (((c >> 3) & 3) << 4) | (f & 15);
  int slot = c & 7;
  int off = ((ftile * 8 + ksg) * 64 + lane) * 8 + slot;
  Bfg[off] = f2bf(Wg[c * 128 + f] * ivg);
  Bfx[off] = f2bf(Wx[c * 128 + f] * ivx);
  if (idx < 128) {
    float ivg2 = gg[idx] * rsqrtf(vg[idx] + 1e-3f);
    float ivx2 = gx[idx] * rsqrtf(vx[idx] + 1e-3f);
    cg[idx] = bg[idx] * ivg2 + beg[idx] - mg[idx] * ivg2;
    cx[idx] = bx[idx] * ivx2 + bex[idx] - mx[idx] * ivx2;
    float ip = gp[0] * rsqrtf(vp[0] + 1e-3f);
    wps[idx] = Wp[idx] * ip;
    if (idx == 0) cps[0] = bp[0] * ip + bep[0] - mp[0] * ip;
  }
}

// ---------------- main fused kernel ----------------
// 512 threads = 8 waves; wave wid owns f-tile wid (16 f), W in registers.
// Each block: 4 consecutive 16-pixel tiles.
__global__ __launch_bounds__(512, 4) void attn_gate_main(
    const float* __restrict__ ing, const float* __restrict__ inx,
    const unsigned short* __restrict__ Wfg, const unsigned short* __restrict__ Wfx,
    const float* __restrict__ cgp, const float* __restrict__ cxp,
    const float* __restrict__ wpp, const float* __restrict__ cpp,
    float* __restrict__ out) {
  // pixT: [buf][tensor][16px][256k] bf16, XOR-swizzled rows (512B rows)
  __shared__ __align__(16) short pixT[2][2][4096];   // 32 KB
  __shared__ __align__(16) float xT[2048];            // 8 KB: [16px][128f], swizzled
  __shared__ __align__(16) float psum[16][8];

  const int tid = threadIdx.x;
  const int lane = tid & 63;
  const int wid = tid >> 6;        // f-tile
  const int l15 = lane & 15, l4 = lane >> 4;

  // ---- W fragments into registers (L2/L3-hot table) ----
  bf16x8 wfg[8], wfx[8];
  #pragma unroll
  for (int ksg = 0; ksg < 8; ++ksg) {
    const int off = ((wid * 8 + ksg) * 64 + lane) * 8;
    wfg[ksg] = *reinterpret_cast<const bf16x8*>(Wfg + off);
    wfx[ksg] = *reinterpret_cast<const bf16x8*>(Wfx + off);
  }
  const int fb = wid * 16 + l4 * 4;  // this lane's 4 consecutive f = fb+reg
  const f32x4 cgv = *reinterpret_cast<const f32x4*>(cgp + fb);
  const f32x4 cxv = *reinterpret_cast<const f32x4*>(cxp + fb);
  const f32x4 wpv = *reinterpret_cast<const f32x4*>(wpp + fb);
  const float cpsv = cpp[0];

  // staging geometry: thread covers (px = tid>>5, k = (tid&31)*8 .. +7)
  const int spx = tid >> 5;
  const int sk0 = (tid & 31) * 8;
  const int swoff = ((spx << 9) | (sk0 << 1)) ^ ((spx & 7) << 4);  // byte in 8KB plane
  const long tile0 = (long)blockIdx.x * 4;

  float4 sg0, sg1, sx0, sx1;
  // ---- prologue: stage tile 0 ----
  {
    const float* g_ = ing + (tile0 * 16 + spx) * 256 + sk0;
    const float* x_ = inx + (tile0 * 16 + spx) * 256 + sk0;
    sg0 = *reinterpret_cast<const float4*>(g_);
    sg1 = *reinterpret_cast<const float4*>(g_ + 4);
    sx0 = *reinterpret_cast<const float4*>(x_);
    sx1 = *reinterpret_cast<const float4*>(x_ + 4);
    *reinterpret_cast<bf16x8*>((char*)&pixT[0][0][0] + swoff) = cvt8(sg0, sg1);
    *reinterpret_cast<bf16x8*>((char*)&pixT[0][1][0] + swoff) = cvt8(sx0, sx1);
  }
  __syncthreads();

  #pragma unroll
  for (int t = 0; t < 4; ++t) {
    const int buf = t & 1;
    // issue next tile's global loads early (hidden under this tile's compute)
    if (t < 3) {
      const float* g_ = ing + ((tile0 + t + 1) * 16 + spx) * 256 + sk0;
      const float* x_ = inx + ((tile0 + t + 1) * 16 + spx) * 256 + sk0;
      sg0 = *reinterpret_cast<const float4*>(g_);
      sg1 = *reinterpret_cast<const float4*>(g_ + 4);
      sx0 = *reinterpret_cast<const float4*>(x_);
      sx1 = *reinterpret_cast<const float4*>(x_ + 4);
    }

    // ---- compute: 16 ds_read + 16 MFMA, zero global loads ----
    f32x4 accg = {0.f, 0.f, 0.f, 0.f}, accx = {0.f, 0.f, 0.f, 0.f};
    #pragma unroll
    for (int ksg = 0; ksg < 8; ++ksg) {
      const int ra = ((l15 << 9) | (ksg << 6) | (l4 << 4)) ^ ((l15 & 7) << 4);
      bf16x8 pg = *reinterpret_cast<const bf16x8*>((const char*)&pixT[buf][0][0] + ra);
      bf16x8 px = *reinterpret_cast<const bf16x8*>((const char*)&pixT[buf][1][0] + ra);
      accg = __builtin_amdgcn_mfma_f32_16x16x32_bf16(wfg[ksg], pg, accg, 0, 0, 0);
      accx = __builtin_amdgcn_mfma_f32_16x16x32_bf16(wfx[ksg], px, accx, 0, 0, 0);
    }

    // ---- epilogue: bias, relu(g+x), psi partials, x-tile transpose ----
    // C/D layout: px = lane&15, f = fb + reg
    f32x4 xv;
    float part = 0.f;
    #pragma unroll
    for (int reg = 0; reg < 4; ++reg) {
      float gv = accg[reg] + cgv[reg];
      xv[reg] = accx[reg] + cxv[reg];
      float s = gv + xv[reg];
      s = s > 0.f ? s : 0.f;
      part += s * wpv[reg];
    }
    part += __shfl_xor(part, 16);   // sum over the 4 l4-groups (16 f of wave)
    part += __shfl_xor(part, 32);
    if (lane < 16) psum[lane][wid] = part;
    const int xoff = ((l15 << 9) | (wid << 6) | (l4 << 4)) ^ ((l15 & 7) << 4);
    *reinterpret_cast<f32x4*>((char*)xT + xoff) = xv;
    __syncthreads();

    // ---- store: psi (redundant per-px sigmoid), coalesced float4 out ----
    {
      const f32x4 pa = *reinterpret_cast<const f32x4*>(&psum[spx][0]);
      const f32x4 pb = *reinterpret_cast<const f32x4*>(&psum[spx][4]);
      const float z = pa[0] + pa[1] + pa[2] + pa[3]
                    + pb[0] + pb[1] + pb[2] + pb[3] + cpsv;
      const float psi = 1.f / (1.f + __expf(-z));
      f32x4 xr = *reinterpret_cast<const f32x4*>((const char*)xT + swoff);
      xr[0] *= psi; xr[1] *= psi; xr[2] *= psi; xr[3] *= psi;
      *reinterpret_cast<f32x4*>(out + ((tile0 + t) * 16 + spx) * 128 + (tid & 31) * 4) = xr;
    }

    // ---- write next tile's staged data, flip buffers ----
    if (t < 3) {
      *reinterpret_cast<bf16x8*>((char*)&pixT[buf ^ 1][0][0] + swoff) = cvt8(sg0, sg1);
      *reinterpret_cast<bf16x8*>((char*)&pixT[buf ^ 1][1][0] + swoff) = cvt8(sx0, sx1);
      __syncthreads();
    }
  }
}

extern "C" void kernel_launch(void* const* d_in, const int* in_sizes, int n_in,
                              void* d_out, int out_size, void* d_ws, size_t ws_size,
                              hipStream_t stream) {
  const float* ing = (const float*)d_in[0];
  const float* inx = (const float*)d_in[1];
  char* ws = (char*)d_ws;
  unsigned short* Bfg = (unsigned short*)ws;                 // 64 KB
  unsigned short* Bfx = (unsigned short*)(ws + 65536);       // 64 KB
  float* cg  = (float*)(ws + 131072);                        // 512 B
  float* cx  = (float*)(ws + 131584);                        // 512 B
  float* wps = (float*)(ws + 132096);                        // 512 B
  float* cps = (float*)(ws + 132608);                        // 4 B

  fold_weights<<<128, 256, 0, stream>>>(
      (const float*)d_in[2],  (const float*)d_in[3],  (const float*)d_in[4],
      (const float*)d_in[5],  (const float*)d_in[6],  (const float*)d_in[7],
      (const float*)d_in[8],  (const float*)d_in[9],  (const float*)d_in[10],
      (const float*)d_in[11], (const float*)d_in[12], (const float*)d_in[13],
      (const float*)d_in[14], (const float*)d_in[15], (const float*)d_in[16],
      (const float*)d_in[17], (const float*)d_in[18], (const float*)d_in[19],
      Bfg, Bfx, cg, cx, wps, cps);

  const int npix = in_sizes[0] / 256;   // 131072
  const int ntiles = npix / 16;         // 8192
  attn_gate_main<<<ntiles / 4, 512, 0, stream>>>(
      ing, inx, Bfg, Bfx, cg, cx, wps, cps, (float*)d_out);
}